// Round 2
// baseline (649.924 us; speedup 1.0000x reference)
//
#include <hip/hip_runtime.h>
#include <hip/hip_bf16.h>

// Qwen2 decoder-layer fragment (Q path only — K/V are dead downstream):
//   h = rmsnorm(x, ln_w); q = h@Wq^T + bq; q = rope(q, pos); out = q@Wo^T + x
// Shapes: x [8192, 3584] fp32, Wq/Wo [3584, 3584] fp32, out fp32 [8192, 3584].
// (out dtype is fp32: reference is an all-fp32 jax pipeline; out_npz ~109MB.)

#define HIDDEN   3584
#define NQ       3584
#define NTOK     8192
#define NPAIR    64
#define EPSV     1e-6f

typedef __hip_bfloat16 bf16;
typedef __bf16 bf16x8 __attribute__((ext_vector_type(8)));
typedef float  f32x4  __attribute__((ext_vector_type(4)));

static __device__ __forceinline__ unsigned short f2bu(float f) {
  bf16 h = __float2bfloat16(f);
  return __builtin_bit_cast(unsigned short, h);
}

static __device__ __forceinline__ void stv(float* p, float v) { *p = v; }
static __device__ __forceinline__ void stv(bf16* p, float v) { *p = __float2bfloat16(v); }

// ---------------- fp32 -> bf16 weight conversion (vectorized) ----------------
__global__ __launch_bounds__(256)
void cvt_f32_bf16(const float* __restrict__ s, bf16* __restrict__ d, int n4) {
  int i = blockIdx.x * 256 + threadIdx.x;
  if (i >= n4) return;
  float4 f = ((const float4*)s)[i];
  ushort4 o;
  o.x = f2bu(f.x); o.y = f2bu(f.y); o.z = f2bu(f.z); o.w = f2bu(f.w);
  ((ushort4*)d)[i] = o;
}

// ---------------- RMSNorm: x fp32 [row, 3584] -> h bf16 ----------------
__global__ __launch_bounds__(256)
void rmsnorm_k(const float* __restrict__ x, const float* __restrict__ w,
               bf16* __restrict__ h) {
  const int row = blockIdx.x;
  const int t = threadIdx.x;
  const float4* xr = (const float4*)(x + (size_t)row * HIDDEN);
  const float4* wr = (const float4*)w;

  float4 v0 = xr[t], v1 = xr[t + 256], v2 = xr[t + 512];
  float4 v3 = make_float4(0.f, 0.f, 0.f, 0.f);
  if (t < 128) v3 = xr[t + 768];

  float ss = v0.x*v0.x + v0.y*v0.y + v0.z*v0.z + v0.w*v0.w
           + v1.x*v1.x + v1.y*v1.y + v1.z*v1.z + v1.w*v1.w
           + v2.x*v2.x + v2.y*v2.y + v2.z*v2.z + v2.w*v2.w
           + v3.x*v3.x + v3.y*v3.y + v3.z*v3.z + v3.w*v3.w;

#pragma unroll
  for (int off = 32; off > 0; off >>= 1) ss += __shfl_down(ss, off);
  __shared__ float red[4];
  if ((t & 63) == 0) red[t >> 6] = ss;
  __syncthreads();
  float tot = red[0] + red[1] + red[2] + red[3];
  float scale = rsqrtf(tot * (1.0f / HIDDEN) + EPSV);

  ushort4* hr = (ushort4*)(h + (size_t)row * HIDDEN);
  float4 w0 = wr[t], w1 = wr[t + 256], w2 = wr[t + 512];
  ushort4 o;
  o.x = f2bu(v0.x*scale*w0.x); o.y = f2bu(v0.y*scale*w0.y);
  o.z = f2bu(v0.z*scale*w0.z); o.w = f2bu(v0.w*scale*w0.w);
  hr[t] = o;
  o.x = f2bu(v1.x*scale*w1.x); o.y = f2bu(v1.y*scale*w1.y);
  o.z = f2bu(v1.z*scale*w1.z); o.w = f2bu(v1.w*scale*w1.w);
  hr[t + 256] = o;
  o.x = f2bu(v2.x*scale*w2.x); o.y = f2bu(v2.y*scale*w2.y);
  o.z = f2bu(v2.z*scale*w2.z); o.w = f2bu(v2.w*scale*w2.w);
  hr[t + 512] = o;
  if (t < 128) {
    float4 w3 = wr[t + 768];
    o.x = f2bu(v3.x*scale*w3.x); o.y = f2bu(v3.y*scale*w3.y);
    o.z = f2bu(v3.z*scale*w3.z); o.w = f2bu(v3.w*scale*w3.w);
    hr[t + 768] = o;
  }
}

// ---------------- per-token rope table: tab[t][i] = (cos, sin) ----------------
__global__ __launch_bounds__(256)
void rope_tab_k(const int* __restrict__ pos, float2* __restrict__ tab) {
  int idx = blockIdx.x * 256 + threadIdx.x;   // NTOK*64
  int t = idx >> 6;
  int i = idx & 63;
  // inv_freq = theta^(-i/64) = exp2(-i/64 * log2(1e6))
  float inv = exp2f(-(float)i * (19.931568569324174f / 64.0f));
  float ang = (float)pos[t] * inv;
  float s, c;
  sincosf(ang, &s, &c);
  tab[idx] = make_float2(c, s);
}

// ---------------- in-place neox rope on q bf16 [NTOK, 28, 128] ----------------
__global__ __launch_bounds__(256)
void rope_apply_k(bf16* __restrict__ q, const float2* __restrict__ tab) {
  const int t = blockIdx.x;
  bf16* qt = q + (size_t)t * NQ;
  const float2* tb = tab + (size_t)t * NPAIR;
  for (int j = threadIdx.x; j < 28 * NPAIR; j += 256) {
    int head = j >> 6;
    int i = j & 63;
    float2 cs = tb[i];
    int base = head * 128 + i;
    float x1 = __bfloat162float(qt[base]);
    float x2 = __bfloat162float(qt[base + 64]);
    qt[base]      = __float2bfloat16(x1 * cs.x - x2 * cs.y);
    qt[base + 64] = __float2bfloat16(x2 * cs.x + x1 * cs.y);
  }
}

// ---------------- bf16 GEMM: C[M,N] = A[M,K] * B[N,K]^T (+ epilogue) ---------
// m97 structure: 128x128 tile, BK=32, 4 waves, 4x4 16x16x32 MFMA frags/wave,
// global_load_lds width-16 staging, linear LDS, 2 barriers per K-step.
// MODE 0: C = OutT(acc + bias[col])            (aux = bias fp32 [N])
// MODE 1: C = OutT(acc + resid[row*N+col])     (aux = residual fp32 [M,N])
#define BM 128
#define BN 128
#define BK 32

template <int MODE, typename OutT>
__global__ __launch_bounds__(256, 2)
void gemm_bt(const bf16* __restrict__ A, const bf16* __restrict__ B,
             const float* __restrict__ aux, OutT* __restrict__ C,
             int M, int N, int K) {
  __shared__ __align__(16) bf16 sA[BM][BK];
  __shared__ __align__(16) bf16 sB[BN][BK];

  const int tid  = threadIdx.x;
  const int wave = tid >> 6;
  const int lane = tid & 63;
  const int wm = wave >> 1;
  const int wn = wave & 1;

  const int bm = blockIdx.y * BM;
  const int bn = blockIdx.x * BN;

  const bf16* Ab = A + (size_t)bm * K;
  const bf16* Bb = B + (size_t)bn * K;

  // staging: wave w covers rows [w*32, w*32+32); one gload_lds = 64 lanes x 16B
  // = 16 rows (4 lanes/row). LDS dest is wave-uniform base + lane*16 (linear).
  const int srow = wave * 32 + (lane >> 2);
  const int scol = (lane & 3) * 8;   // elements

  f32x4 acc[4][4];
#pragma unroll
  for (int i = 0; i < 4; ++i)
#pragma unroll
    for (int j = 0; j < 4; ++j)
      acc[i][j] = (f32x4){0.f, 0.f, 0.f, 0.f};

  // fragment read: row/col = lane&15, k = 8*(lane>>4) + 0..7 (contiguous)
  const int fr = lane & 15;
  const int fk = (lane >> 4) * 8;

  for (int k0 = 0; k0 < K; k0 += BK) {
#pragma unroll
    for (int j = 0; j < 2; ++j) {
      const bf16* gA = Ab + (size_t)(srow + j * 16) * K + (k0 + scol);
      __builtin_amdgcn_global_load_lds(
          (const __attribute__((address_space(1))) void*)gA,
          (__attribute__((address_space(3))) void*)&sA[wave * 32 + j * 16][0],
          16, 0, 0);
      const bf16* gB = Bb + (size_t)(srow + j * 16) * K + (k0 + scol);
      __builtin_amdgcn_global_load_lds(
          (const __attribute__((address_space(1))) void*)gB,
          (__attribute__((address_space(3))) void*)&sB[wave * 32 + j * 16][0],
          16, 0, 0);
    }
    __syncthreads();

    bf16x8 af[4], bfv[4];
#pragma unroll
    for (int i = 0; i < 4; ++i) {
      af[i]  = *(const bf16x8*)&sA[wm * 64 + i * 16 + fr][fk];
      bfv[i] = *(const bf16x8*)&sB[wn * 64 + i * 16 + fr][fk];
    }
#pragma unroll
    for (int i = 0; i < 4; ++i)
#pragma unroll
      for (int j = 0; j < 4; ++j)
        acc[i][j] = __builtin_amdgcn_mfma_f32_16x16x32_bf16(
            af[i], bfv[j], acc[i][j], 0, 0, 0);
    __syncthreads();
  }

  // C/D layout: col = lane&15, row = 4*(lane>>4) + reg
  const int rbase = bm + wm * 64 + (lane >> 4) * 4;
  const int cbase = bn + wn * 64 + (lane & 15);
#pragma unroll
  for (int i = 0; i < 4; ++i) {
#pragma unroll
    for (int j = 0; j < 4; ++j) {
      const int col = cbase + j * 16;
#pragma unroll
      for (int r = 0; r < 4; ++r) {
        const int row = rbase + i * 16 + r;
        float v = acc[i][j][r];
        if (MODE == 0) v += aux[col];
        else           v += aux[(size_t)row * N + col];
        stv(&C[(size_t)row * N + col], v);
      }
    }
  }
}

// ---------------- launch ----------------
extern "C" void kernel_launch(void* const* d_in, const int* in_sizes, int n_in,
                              void* d_out, int out_size, void* d_ws, size_t ws_size,
                              hipStream_t stream) {
  (void)in_sizes; (void)n_in; (void)out_size; (void)ws_size;
  const float* x    = (const float*)d_in[0];
  const int*   pos  = (const int*)d_in[1];
  const float* ln_w = (const float*)d_in[2];
  const float* Wq   = (const float*)d_in[3];
  const float* bq   = (const float*)d_in[4];
  const float* Wo   = (const float*)d_in[9];
  float* out = (float*)d_out;   // reference output dtype is float32

  char* ws = (char*)d_ws;
  size_t off = 0;
  bf16* h    = (bf16*)(ws + off); off += (size_t)NTOK * HIDDEN * sizeof(bf16);
  bf16* q    = (bf16*)(ws + off); off += (size_t)NTOK * NQ * sizeof(bf16);
  bf16* Wqb  = (bf16*)(ws + off); off += (size_t)NQ * HIDDEN * sizeof(bf16);
  bf16* Wob  = (bf16*)(ws + off); off += (size_t)HIDDEN * NQ * sizeof(bf16);
  float2* tab = (float2*)(ws + off); off += (size_t)NTOK * NPAIR * sizeof(float2);

  const int n4 = NQ * HIDDEN / 4;
  cvt_f32_bf16<<<(n4 + 255) / 256, 256, 0, stream>>>(Wq, Wqb, n4);
  cvt_f32_bf16<<<(n4 + 255) / 256, 256, 0, stream>>>(Wo, Wob, n4);
  rmsnorm_k<<<NTOK, 256, 0, stream>>>(x, ln_w, h);
  rope_tab_k<<<(NTOK * NPAIR) / 256, 256, 0, stream>>>(pos, tab);

  dim3 g1(NQ / BN, NTOK / BM);
  gemm_bt<0, bf16><<<g1, 256, 0, stream>>>(h, Wqb, bq, q, NTOK, NQ, HIDDEN);
  rope_apply_k<<<NTOK, 256, 0, stream>>>(q, tab);
  dim3 g2(HIDDEN / BN, NTOK / BM);
  gemm_bt<1, float><<<g2, 256, 0, stream>>>(q, Wob, x, out, NTOK, HIDDEN, NQ);
}